// Round 21
// baseline (527.920 us; speedup 1.0000x reference)
//
#include <hip/hip_runtime.h>
#include <cstdint>
#include <cstddef>

typedef __attribute__((ext_vector_type(8))) _Float16 half8;
typedef __attribute__((ext_vector_type(4))) _Float16 half4;
typedef __attribute__((ext_vector_type(4))) float f32x4;

#define DEV static __device__ __forceinline__
#define AS1(p) (const __attribute__((address_space(1))) void*)(p)
#define AS3(p) (__attribute__((address_space(3))) void*)(p)

#define LDS_BARRIER() asm volatile("s_waitcnt lgkmcnt(0)\n\ts_barrier" ::: "memory")

DEV half8 cvt8(const float* p) {
    f32x4 a = *(const f32x4*)p;
    f32x4 b = *(const f32x4*)(p + 4);
    half8 o;
    o[0] = (_Float16)a[0]; o[1] = (_Float16)a[1];
    o[2] = (_Float16)a[2]; o[3] = (_Float16)a[3];
    o[4] = (_Float16)b[0]; o[5] = (_Float16)b[1];
    o[6] = (_Float16)b[2]; o[7] = (_Float16)b[3];
    return o;
}

// ---- prep: fused V-projection (blocks 0..127) + f32->f16 conversions ----
__global__ __launch_bounds__(256, 2)
void prep_kernel(const float* __restrict__ v, const float* __restrict__ Wv,
                 const float* __restrict__ bv, _Float16* __restrict__ VT,
                 const float* __restrict__ q, _Float16* __restrict__ oq,
                 const float* __restrict__ k, _Float16* __restrict__ ok,
                 const float* __restrict__ wq, _Float16* __restrict__ owq,
                 const float* __restrict__ wk, _Float16* __restrict__ owk,
                 const float* __restrict__ wo, _Float16* __restrict__ owo)
{
    __shared__ _Float16 Asl[64][40];
    __shared__ _Float16 Bsl[64][40];

    if (blockIdx.x < 128) {
        const int tid = threadIdx.x;
        const int l = tid & 63, w = tid >> 6;
        const int wr = w >> 1, wc = w & 1;
        const int lr = l & 15, lh = l >> 4;
        const int bm0 = blockIdx.x * 64;
        const int K = 1024;

        f32x4 acc[2][2] = {};

        for (int k0 = 0; k0 < K; k0 += 32) {
            __syncthreads();
            for (int c = tid; c < 256; c += 256) {
                int row = c >> 2, c8 = (c & 3) << 3;
                *(half8*)&Asl[row][c8] = cvt8(v + (size_t)(bm0 + row) * K + k0 + c8);
            }
            {
                int c = tid;
                if (c < 256) {
                    int row = c >> 2, c8 = (c & 3) << 3;
                    *(half8*)&Bsl[row][c8] = cvt8(Wv + (size_t)row * K + k0 + c8);
                }
            }
            __syncthreads();

            half8 a[2], b[2];
#pragma unroll
            for (int m = 0; m < 2; m++)
                a[m] = *(const half8*)&Asl[wr * 32 + m * 16 + lr][lh * 8];
#pragma unroll
            for (int n = 0; n < 2; n++)
                b[n] = *(const half8*)&Bsl[wc * 32 + n * 16 + lr][lh * 8];
#pragma unroll
            for (int m = 0; m < 2; m++)
#pragma unroll
                for (int n = 0; n < 2; n++)
                    acc[m][n] = __builtin_amdgcn_mfma_f32_16x16x32_f16(a[m], b[n], acc[m][n], 0, 0, 0);
        }

#pragma unroll
        for (int m = 0; m < 2; m++)
#pragma unroll
            for (int n = 0; n < 2; n++) {
                int row0 = bm0 + wr * 32 + m * 16 + lh * 4;
                int col = wc * 32 + n * 16 + lr;
                float bvv = bv[col];
#pragma unroll
                for (int j = 0; j < 4; j++) {
                    float val = acc[m][n][j] + bvv;
                    int row = row0 + j;
                    int bi = row >> 11, t = row & 2047;
                    VT[(((size_t)(bi * 64 + col)) << 11) + t] = (_Float16)val;
                }
            }
    } else {
        const int NQ = 1048576, NW = 131072;
        const int total = 2 * NQ + 3 * NW;
        int i = (blockIdx.x - 128) * 256 + threadIdx.x;
        int stride = 2048 * 256;
        for (; i < total; i += stride) {
            if (i < NQ)            ((half8*)oq)[i] = cvt8(q + (size_t)i * 8);
            else if (i < 2 * NQ)   ((half8*)ok)[i - NQ] = cvt8(k + (size_t)(i - NQ) * 8);
            else {
                int j = i - 2 * NQ;
                if (j < NW)        ((half8*)owq)[j] = cvt8(wq + (size_t)j * 8);
                else if (j < 2*NW) ((half8*)owk)[j - NW] = cvt8(wk + (size_t)(j - NW) * 8);
                else               ((half8*)owo)[j - 2*NW] = cvt8(wo + (size_t)(j - 2*NW) * 8);
            }
        }
    }
}

// ---- f16 GEMM core, BK=64: 16 barriers for K=1024 (was 32), 32 MFMA/step.
// LDS: 2 bufs x 8 chunks x 128 rows x 16B = 32KB per matrix -> 64KB total,
// 2 blocks/CU. Chunk-transposed [chunk][128] layout, linear gll writes.
#define STAGE(buf, t) do {                                                        \
        int k0 = (t) << 6;                                                        \
        _Pragma("unroll")                                                         \
        for (int c2 = 0; c2 < 2; c2++) {                                          \
            int chunk = w * 2 + c2;                                               \
            _Pragma("unroll")                                                     \
            for (int q2 = 0; q2 < 2; q2++) {                                      \
                int r = q2 * 64 + l;                                              \
                __builtin_amdgcn_global_load_lds(                                 \
                    AS1(A + (size_t)(bm0 + r) * K + k0 + chunk * 8),              \
                    AS3(&As[buf][chunk * 128 + q2 * 64]), 16, 0, 0);              \
                __builtin_amdgcn_global_load_lds(                                 \
                    AS1(B + (size_t)(bn0 + r) * K + k0 + chunk * 8),              \
                    AS3(&Bs[buf][chunk * 128 + q2 * 64]), 16, 0, 0);              \
            }                                                                     \
        }                                                                         \
    } while (0)

#define GEMM_CORE(BM0, BN0, OUTSTMT)                                              \
    const int tid = threadIdx.x, l = tid & 63, w = tid >> 6;                      \
    const int lr = l & 15, lh = l >> 4;                                           \
    const int wm0 = (w >> 1) * 64, wn0 = (w & 1) * 64;                            \
    const int bm0 = (BM0), bn0 = (BN0);                                           \
    const int nsteps = K >> 6;                                                    \
    f32x4 acc[4][4] = {};                                                         \
    STAGE(0, 0);                                                                  \
    __syncthreads();                                                              \
    for (int t = 0; t < nsteps; t++) {                                            \
        int cur = t & 1;                                                          \
        if (t + 1 < nsteps) STAGE(cur ^ 1, t + 1);                                \
        _Pragma("unroll")                                                         \
        for (int half = 0; half < 2; half++) {                                    \
            half8 a[4], b[4];                                                     \
            _Pragma("unroll")                                                     \
            for (int m = 0; m < 4; m++)                                           \
                a[m] = As[cur][(half * 4 + lh) * 128 + wm0 + m * 16 + lr];        \
            _Pragma("unroll")                                                     \
            for (int n = 0; n < 4; n++)                                           \
                b[n] = Bs[cur][(half * 4 + lh) * 128 + wn0 + n * 16 + lr];        \
            _Pragma("unroll")                                                     \
            for (int m = 0; m < 4; m++)                                           \
                _Pragma("unroll")                                                 \
                for (int n = 0; n < 4; n++)                                       \
                    acc[m][n] = __builtin_amdgcn_mfma_f32_16x16x32_f16(           \
                        a[m], b[n], acc[m][n], 0, 0, 0);                          \
        }                                                                         \
        __syncthreads();                                                          \
    }                                                                             \
    _Pragma("unroll")                                                             \
    for (int m = 0; m < 4; m++)                                                   \
        _Pragma("unroll")                                                         \
        for (int n = 0; n < 4; n++) {                                             \
            int row0 = bm0 + wm0 + m * 16 + lh * 4;                               \
            int col = bn0 + wn0 + n * 16 + lr;                                    \
            float bvv = bias[col];                                                \
            _Pragma("unroll")                                                     \
            for (int j = 0; j < 4; j++) {                                         \
                float val = (acc[m][n][j] + bvv) * scale;                         \
                int row = row0 + j;                                               \
                OUTSTMT;                                                          \
            }                                                                     \
        }

__global__ __launch_bounds__(256, 2)
void gemm16_dual(const _Float16* __restrict__ A0, const _Float16* __restrict__ B0,
                 const float* __restrict__ bias0, float scale0, _Float16* __restrict__ C0,
                 const _Float16* __restrict__ A1, const _Float16* __restrict__ B1,
                 const float* __restrict__ bias1, float scale1, _Float16* __restrict__ C1,
                 int M, int N, int K)
{
    __shared__ half8 As[2][1024];
    __shared__ half8 Bs[2][1024];
    const _Float16* A = blockIdx.z ? A1 : A0;
    const _Float16* B = blockIdx.z ? B1 : B0;
    const float* bias = blockIdx.z ? bias1 : bias0;
    float scale = blockIdx.z ? scale1 : scale0;
    _Float16* Cout = blockIdx.z ? C1 : C0;
    GEMM_CORE(blockIdx.x * 128, blockIdx.y * 128,
              Cout[(size_t)row * N + col] = (_Float16)val)
}

// ---- ygc: y-GEMM (blocks 0..511) + combine (blocks 512..1023) ----
__global__ __launch_bounds__(256, 2)
void ygc_kernel(const _Float16* __restrict__ A, const _Float16* __restrict__ B,
                const float* __restrict__ bias, float scale, float* __restrict__ Cout,
                int M, int N, int K,
                const _Float16* __restrict__ p0, const _Float16* __restrict__ p1,
                float* __restrict__ amean, int n8)
{
    __shared__ half8 As[2][1024];
    __shared__ half8 Bs[2][1024];
    if (blockIdx.x < 512) {
        const int bid = blockIdx.x;
        GEMM_CORE((bid & 63) * 128, (bid >> 6) * 128,
                  Cout[(size_t)row * N + col] = val)
    } else {
        int i = (blockIdx.x - 512) * 256 + threadIdx.x;
        int stride = 512 * 256;
        for (; i < n8; i += stride) {
            half8 x = ((const half8*)p0)[i];
            half8 y = ((const half8*)p1)[i];
            f32x4 o0, o1;
#pragma unroll
            for (int j = 0; j < 4; j++) o0[j] = ((float)x[j] + (float)y[j]) * 0.0625f;
#pragma unroll
            for (int j = 0; j < 4; j++) o1[j] = ((float)x[j + 4] + (float)y[j + 4]) * 0.0625f;
            *(f32x4*)(amean + (size_t)i * 8) = o0;
            *(f32x4*)(amean + (size_t)i * 8 + 4) = o1;
        }
    }
}
#undef STAGE

// K-fragment loader: dst[kfr][dk], 4 x 16B global loads
#define LK(dst, kt) do {                                                          \
        const _Float16* kp_ = Kb + (size_t)((kt) * 32) * 1024;                    \
        _Pragma("unroll")                                                         \
        for (int kfr_ = 0; kfr_ < 2; kfr_++)                                      \
            _Pragma("unroll")                                                     \
            for (int dk_ = 0; dk_ < 2; dk_++)                                     \
                dst[kfr_][dk_] = *(const half8*)(kp_ + (size_t)(kfr_ * 16 + lr) * 1024 \
                                                 + ch + dk_ * 32 + lh * 8);       \
    } while (0)

#define SBODY(KF) do {                                                            \
        f32x4 sc[2][2] = {};                                                      \
        _Pragma("unroll")                                                         \
        for (int m = 0; m < 2; m++)                                               \
            _Pragma("unroll")                                                     \
            for (int kfr = 0; kfr < 2; kfr++)                                     \
                _Pragma("unroll")                                                 \
                for (int dk = 0; dk < 2; dk++)                                    \
                    sc[m][kfr] = __builtin_amdgcn_mfma_f32_16x16x32_f16(          \
                        qf[m][dk], KF[kfr][dk], sc[m][kfr], 0, 0, 0);             \
        _Pragma("unroll")                                                         \
        for (int m = 0; m < 2; m++)                                               \
            _Pragma("unroll")                                                     \
            for (int j = 0; j < 4; j++)                                           \
                sl[m][j] += __builtin_amdgcn_exp2f(sc[m][0][j])                   \
                          + __builtin_amdgcn_exp2f(sc[m][1][j]);                  \
    } while (0)

// ---- fused attention (R18 exact): phase 1 denominators, phase 2 emit ----
__global__ __launch_bounds__(512, 4)
void attn_fused(const _Float16* __restrict__ Qh, const _Float16* __restrict__ Kh,
                const _Float16* __restrict__ VT, _Float16* __restrict__ attnp,
                _Float16* __restrict__ Op)
{
    const int blk = blockIdx.x;
    const int b = blk & 3;
    const int hg = (blk >> 2) & 1;
    const int q0 = (blk >> 3) << 5;
    const int tid = threadIdx.x;
    const int l = tid & 63, w = tid >> 6;
    const int lr = l & 15, lh = l >> 4;
    const int ch = (hg * 8 + w) * 64;

    __shared__ __align__(16) _Float16 Pld[2][8][32][40];

    const size_t base = (size_t)b * 2048 * 1024;
    const _Float16* Qb = Qh + base;
    const _Float16* Kb = Kh + base;

    half8 qf[2][2];
#pragma unroll
    for (int m = 0; m < 2; m++)
#pragma unroll
        for (int dk = 0; dk < 2; dk++)
            qf[m][dk] = *(const half8*)(Qb + (size_t)(q0 + m * 16 + lr) * 1024
                                        + ch + dk * 32 + lh * 8);

    // ---- phase 1 ----
    float sl[2][4] = {};
    {
        half8 ka[2][2], kb2[2][2];
        LK(ka, 0);
        for (int kt = 0; kt < 64; kt += 2) {
            LK(kb2, kt + 1);
            SBODY(ka);
            LK(ka, kt + 2 < 64 ? kt + 2 : 63);
            SBODY(kb2);
        }
    }
#pragma unroll
    for (int m = 0; m < 2; m++)
#pragma unroll
        for (int j = 0; j < 4; j++) {
            float s = sl[m][j];
#pragma unroll
            for (int d = 1; d < 16; d <<= 1)
                s += __shfl_xor(s, d, 64);
            sl[m][j] = s;
        }
    float rinv[2];
#pragma unroll
    for (int m = 0; m < 2; m++) {
        int src = (lr >> 2) << 4;
        float t0 = __shfl(sl[m][0], src, 64);
        float t1 = __shfl(sl[m][1], src, 64);
        float t2 = __shfl(sl[m][2], src, 64);
        float t3 = __shfl(sl[m][3], src, 64);
        int jj = lr & 3;
        float s = (jj == 0) ? t0 : (jj == 1) ? t1 : (jj == 2) ? t2 : t3;
        rinv[m] = 1.0f / s;
    }

    // ---- phase 2 ----
    f32x4 oacc[2][4] = {};
    half8 ka[2][2], kb2[2][2];

#define EBODY(KF, KT, P) do {                                                     \
        const int krow = (KT) * 32;                                               \
        f32x4 sc[2][2] = {};                                                      \
        _Pragma("unroll")                                                         \
        for (int m = 0; m < 2; m++)                                               \
            _Pragma("unroll")                                                     \
            for (int kfr = 0; kfr < 2; kfr++)                                     \
                _Pragma("unroll")                                                 \
                for (int dk = 0; dk < 2; dk++)                                    \
                    sc[m][kfr] = __builtin_amdgcn_mfma_f32_16x16x32_f16(          \
                        KF[kfr][dk], qf[m][dk], sc[m][kfr], 0, 0, 0);             \
        _Pragma("unroll")                                                         \
        for (int m = 0; m < 2; m++)                                               \
            _Pragma("unroll")                                                     \
            for (int kfr = 0; kfr < 2; kfr++) {                                   \
                half4 pk4;                                                        \
                _Pragma("unroll")                                                 \
                for (int j = 0; j < 4; j++)                                       \
                    pk4[j] = (_Float16)(__builtin_amdgcn_exp2f(sc[m][kfr][j])     \
                                        * rinv[m]);                               \
                *(half4*)&Pld[P][w][m * 16 + lr][kfr * 16 + lh * 4] = pk4;        \
            }                                                                     \
        half8 vf[4], pa[2];                                                       \
        _Pragma("unroll")                                                         \
        for (int dv = 0; dv < 4; dv++)                                            \
            vf[dv] = *(const half8*)(VT + (((size_t)(b * 64 + dv * 16 + lr)) << 11) + krow + lh * 8); \
        _Pragma("unroll")                                                         \
        for (int m = 0; m < 2; m++)                                               \
            pa[m] = *(const half8*)&Pld[P][w][m * 16 + lr][lh * 8];               \
        _Pragma("unroll")                                                         \
        for (int m = 0; m < 2; m++)                                               \
            _Pragma("unroll")                                                     \
            for (int dv = 0; dv < 4; dv++)                                        \
                oacc[m][dv] = __builtin_amdgcn_mfma_f32_16x16x32_f16(             \
                    pa[m], vf[dv], oacc[m][dv], 0, 0, 0);                         \
        LDS_BARRIER();                                                            \
        {                                                                         \
            int r = tid >> 4, c2 = (tid & 15) * 2;                                \
            float s0 = 0.f, s1 = 0.f;                                             \
            _Pragma("unroll")                                                     \
            for (int ww = 0; ww < 8; ww++) {                                      \
                union { uint32_t u; _Float16 h[2]; } pv;                          \
                pv.u = *(const uint32_t*)&Pld[P][ww][r][c2];                      \
                s0 += (float)pv.h[0]; s1 += (float)pv.h[1];                       \
            }                                                                     \
            union { _Float16 h[2]; uint32_t u; } pk;                              \
            pk.h[0] = (_Float16)s0; pk.h[1] = (_Float16)s1;                       \
            __builtin_nontemporal_store(pk.u, (uint32_t*)(attnp                   \
                + (size_t)hg * 16777216 + (((size_t)(b * 2048 + q0 + r)) << 11)   \
                + krow + c2));                                                    \
        }                                                                         \
    } while (0)

    LK(ka, 0);
    for (int i = 0; i < 64; i += 2) {
        LK(kb2, i + 1);
        EBODY(ka, i, 0);
        LK(ka, i + 2 < 64 ? i + 2 : 63);
        EBODY(kb2, i + 1, 1);
    }
#undef EBODY

    _Float16* op = Op + base;
#pragma unroll
    for (int m = 0; m < 2; m++)
#pragma unroll
        for (int dv = 0; dv < 4; dv++)
#pragma unroll
            for (int j = 0; j < 4; j++) {
                int row = q0 + m * 16 + lh * 4 + j;
                int col = ch + dv * 16 + lr;
                op[(size_t)row * 1024 + col] = (_Float16)oacc[m][dv][j];
            }
}

extern "C" void kernel_launch(void* const* d_in, const int* in_sizes, int n_in,
                              void* d_out, int out_size, void* d_ws, size_t ws_size,
                              hipStream_t stream)
{
    const float* q  = (const float*)d_in[0];
    const float* k  = (const float*)d_in[1];
    const float* v  = (const float*)d_in[2];
    const float* Wq = (const float*)d_in[3];
    const float* bq = (const float*)d_in[4];
    const float* Wk = (const float*)d_in[5];
    const float* bk = (const float*)d_in[6];
    const float* Wv = (const float*)d_in[7];
    const float* bv = (const float*)d_in[8];
    const float* Wo = (const float*)d_in[9];
    const float* bo = (const float*)d_in[10];

    float* y = (float*)d_out;
    float* attn_mean = y + (size_t)4 * 2048 * 1024;

    uint8_t* ws = (uint8_t*)d_ws;
    _Float16* Qh  = (_Float16*)(ws);                         // 16 MB @ 0
    _Float16* Kh  = (_Float16*)(ws + 16777216);              // 16 MB
    _Float16* VT  = (_Float16*)(ws + 33554432);              // 1 MB
    _Float16* Wqc = (_Float16*)(ws + 34603008);              // 2 MB
    _Float16* Wkc = (_Float16*)(ws + 36700160);              // 2 MB
    _Float16* Woc = (_Float16*)(ws + 38797312);              // 2 MB
    _Float16* qc  = (_Float16*)(ws + 40894464);              // 16 MB (becomes Op)
    _Float16* kc  = (_Float16*)(ws + 57671680);              // 16 MB
    _Float16* Op  = qc;
    _Float16* attnp = (_Float16*)(ws + 74448896);            // 64 MB (2 hg partials)

    const float QS = 0.125f * 1.44269504088896340736f;

    prep_kernel<<<dim3(2176), dim3(256), 0, stream>>>(
        v, Wv, bv, VT, q, qc, k, kc, Wq, Wqc, Wk, Wkc, Wo, Woc);

    gemm16_dual<<<dim3(64, 8, 2), dim3(256), 0, stream>>>(
        qc, Wqc, bq, QS, Qh, kc, Wkc, bk, 1.0f, Kh, 8192, 1024, 1024);

    attn_fused<<<dim3(512), dim3(512), 0, stream>>>(Qh, Kh, VT, attnp, Op);

    ygc_kernel<<<dim3(1024), dim3(256), 0, stream>>>(
        Op, Woc, bo, 1.0f, y, 8192, 1024, 1024,
        attnp, attnp + (size_t)16777216, attn_mean, 2097152);
}

// Round 22
// 512.785 us; speedup vs baseline: 1.0295x; 1.0295x over previous
//
#include <hip/hip_runtime.h>
#include <cstdint>
#include <cstddef>

typedef __attribute__((ext_vector_type(8))) _Float16 half8;
typedef __attribute__((ext_vector_type(4))) _Float16 half4;
typedef __attribute__((ext_vector_type(4))) float f32x4;

#define DEV static __device__ __forceinline__
#define AS1(p) (const __attribute__((address_space(1))) void*)(p)
#define AS3(p) (__attribute__((address_space(3))) void*)(p)

#define LDS_BARRIER() asm volatile("s_waitcnt lgkmcnt(0)\n\ts_barrier" ::: "memory")

DEV half8 cvt8(const float* p) {
    f32x4 a = *(const f32x4*)p;
    f32x4 b = *(const f32x4*)(p + 4);
    half8 o;
    o[0] = (_Float16)a[0]; o[1] = (_Float16)a[1];
    o[2] = (_Float16)a[2]; o[3] = (_Float16)a[3];
    o[4] = (_Float16)b[0]; o[5] = (_Float16)b[1];
    o[6] = (_Float16)b[2]; o[7] = (_Float16)b[3];
    return o;
}

// ---- prep: fused V-projection (blocks 0..127) + f32->f16 conversions ----
__global__ __launch_bounds__(256, 2)
void prep_kernel(const float* __restrict__ v, const float* __restrict__ Wv,
                 const float* __restrict__ bv, _Float16* __restrict__ VT,
                 const float* __restrict__ q, _Float16* __restrict__ oq,
                 const float* __restrict__ k, _Float16* __restrict__ ok,
                 const float* __restrict__ wq, _Float16* __restrict__ owq,
                 const float* __restrict__ wk, _Float16* __restrict__ owk,
                 const float* __restrict__ wo, _Float16* __restrict__ owo)
{
    __shared__ _Float16 Asl[64][40];
    __shared__ _Float16 Bsl[64][40];

    if (blockIdx.x < 128) {
        const int tid = threadIdx.x;
        const int l = tid & 63, w = tid >> 6;
        const int wr = w >> 1, wc = w & 1;
        const int lr = l & 15, lh = l >> 4;
        const int bm0 = blockIdx.x * 64;
        const int K = 1024;

        f32x4 acc[2][2] = {};

        for (int k0 = 0; k0 < K; k0 += 32) {
            __syncthreads();
            for (int c = tid; c < 256; c += 256) {
                int row = c >> 2, c8 = (c & 3) << 3;
                *(half8*)&Asl[row][c8] = cvt8(v + (size_t)(bm0 + row) * K + k0 + c8);
            }
            {
                int c = tid;
                if (c < 256) {
                    int row = c >> 2, c8 = (c & 3) << 3;
                    *(half8*)&Bsl[row][c8] = cvt8(Wv + (size_t)row * K + k0 + c8);
                }
            }
            __syncthreads();

            half8 a[2], b[2];
#pragma unroll
            for (int m = 0; m < 2; m++)
                a[m] = *(const half8*)&Asl[wr * 32 + m * 16 + lr][lh * 8];
#pragma unroll
            for (int n = 0; n < 2; n++)
                b[n] = *(const half8*)&Bsl[wc * 32 + n * 16 + lr][lh * 8];
#pragma unroll
            for (int m = 0; m < 2; m++)
#pragma unroll
                for (int n = 0; n < 2; n++)
                    acc[m][n] = __builtin_amdgcn_mfma_f32_16x16x32_f16(a[m], b[n], acc[m][n], 0, 0, 0);
        }

#pragma unroll
        for (int m = 0; m < 2; m++)
#pragma unroll
            for (int n = 0; n < 2; n++) {
                int row0 = bm0 + wr * 32 + m * 16 + lh * 4;
                int col = wc * 32 + n * 16 + lr;
                float bvv = bv[col];
#pragma unroll
                for (int j = 0; j < 4; j++) {
                    float val = acc[m][n][j] + bvv;
                    int row = row0 + j;
                    int bi = row >> 11, t = row & 2047;
                    VT[(((size_t)(bi * 64 + col)) << 11) + t] = (_Float16)val;
                }
            }
    } else {
        const int NQ = 1048576, NW = 131072;
        const int total = 2 * NQ + 3 * NW;
        int i = (blockIdx.x - 128) * 256 + threadIdx.x;
        int stride = 2048 * 256;
        for (; i < total; i += stride) {
            if (i < NQ)            ((half8*)oq)[i] = cvt8(q + (size_t)i * 8);
            else if (i < 2 * NQ)   ((half8*)ok)[i - NQ] = cvt8(k + (size_t)(i - NQ) * 8);
            else {
                int j = i - 2 * NQ;
                if (j < NW)        ((half8*)owq)[j] = cvt8(wq + (size_t)j * 8);
                else if (j < 2*NW) ((half8*)owk)[j - NW] = cvt8(wk + (size_t)(j - NW) * 8);
                else               ((half8*)owo)[j - 2*NW] = cvt8(wo + (size_t)(j - 2*NW) * 8);
            }
        }
    }
}

// ---- dual f16 GEMM (Q/K projections), gll staging, 128x128, BK=32 ----
#define STAGE(buf, t) do {                                                        \
        int k0 = (t) << 5;                                                        \
        _Pragma("unroll")                                                         \
        for (int q2 = 0; q2 < 2; q2++) {                                          \
            int r = q2 * 64 + l;                                                  \
            __builtin_amdgcn_global_load_lds(                                     \
                AS1(A + (size_t)(bm0 + r) * K + k0 + w * 8),                      \
                AS3(&As[buf][w * 128 + q2 * 64]), 16, 0, 0);                      \
            __builtin_amdgcn_global_load_lds(                                     \
                AS1(B + (size_t)(bn0 + r) * K + k0 + w * 8),                      \
                AS3(&Bs[buf][w * 128 + q2 * 64]), 16, 0, 0);                      \
        }                                                                         \
    } while (0)

#define GEMM_CORE(BM0, BN0, OUTSTMT)                                              \
    const int tid = threadIdx.x, l = tid & 63, w = tid >> 6;                      \
    const int lr = l & 15, lh = l >> 4;                                           \
    const int wm0 = (w >> 1) * 64, wn0 = (w & 1) * 64;                            \
    const int bm0 = (BM0), bn0 = (BN0);                                           \
    const int nsteps = K >> 5;                                                    \
    f32x4 acc[4][4] = {};                                                         \
    STAGE(0, 0);                                                                  \
    __syncthreads();                                                              \
    for (int t = 0; t < nsteps; t++) {                                            \
        int cur = t & 1;                                                          \
        if (t + 1 < nsteps) STAGE(cur ^ 1, t + 1);                                \
        half8 a[4], b[4];                                                         \
        _Pragma("unroll")                                                         \
        for (int m = 0; m < 4; m++) a[m] = As[cur][lh * 128 + wm0 + m * 16 + lr]; \
        _Pragma("unroll")                                                         \
        for (int n = 0; n < 4; n++) b[n] = Bs[cur][lh * 128 + wn0 + n * 16 + lr]; \
        _Pragma("unroll")                                                         \
        for (int m = 0; m < 4; m++)                                               \
            _Pragma("unroll")                                                     \
            for (int n = 0; n < 4; n++)                                           \
                acc[m][n] = __builtin_amdgcn_mfma_f32_16x16x32_f16(a[m], b[n], acc[m][n], 0, 0, 0); \
        __syncthreads();                                                          \
    }                                                                             \
    _Pragma("unroll")                                                             \
    for (int m = 0; m < 4; m++)                                                   \
        _Pragma("unroll")                                                         \
        for (int n = 0; n < 4; n++) {                                             \
            int row0 = bm0 + wm0 + m * 16 + lh * 4;                               \
            int col = bn0 + wn0 + n * 16 + lr;                                    \
            float bvv = bias[col];                                                \
            _Pragma("unroll")                                                     \
            for (int j = 0; j < 4; j++) {                                         \
                float val = (acc[m][n][j] + bvv) * scale;                         \
                int row = row0 + j;                                               \
                OUTSTMT;                                                          \
            }                                                                     \
        }

__global__ __launch_bounds__(256, 2)
void gemm16_dual(const _Float16* __restrict__ A0, const _Float16* __restrict__ B0,
                 const float* __restrict__ bias0, float scale0, _Float16* __restrict__ C0,
                 const _Float16* __restrict__ A1, const _Float16* __restrict__ B1,
                 const float* __restrict__ bias1, float scale1, _Float16* __restrict__ C1,
                 int M, int N, int K)
{
    __shared__ half8 As[2][512];
    __shared__ half8 Bs[2][512];
    const _Float16* A = blockIdx.z ? A1 : A0;
    const _Float16* B = blockIdx.z ? B1 : B0;
    const float* bias = blockIdx.z ? bias1 : bias0;
    float scale = blockIdx.z ? scale1 : scale0;
    _Float16* Cout = blockIdx.z ? C1 : C0;
    GEMM_CORE(blockIdx.x * 128, blockIdx.y * 128,
              Cout[(size_t)row * N + col] = (_Float16)val)
}

// ---- ygc: y-GEMM (blocks 0..511) + combine (blocks 512..1023) ----
__global__ __launch_bounds__(256, 2)
void ygc_kernel(const _Float16* __restrict__ A, const _Float16* __restrict__ B,
                const float* __restrict__ bias, float scale, float* __restrict__ Cout,
                int M, int N, int K,
                const _Float16* __restrict__ p0, const _Float16* __restrict__ p1,
                float* __restrict__ amean, int n8)
{
    __shared__ half8 As[2][512];
    __shared__ half8 Bs[2][512];
    if (blockIdx.x < 512) {
        const int bid = blockIdx.x;
        GEMM_CORE((bid & 63) * 128, (bid >> 6) * 128,
                  Cout[(size_t)row * N + col] = val)
    } else {
        int i = (blockIdx.x - 512) * 256 + threadIdx.x;
        int stride = 512 * 256;
        for (; i < n8; i += stride) {
            half8 x = ((const half8*)p0)[i];
            half8 y = ((const half8*)p1)[i];
            f32x4 o0, o1;
#pragma unroll
            for (int j = 0; j < 4; j++) o0[j] = ((float)x[j] + (float)y[j]) * 0.0625f;
#pragma unroll
            for (int j = 0; j < 4; j++) o1[j] = ((float)x[j + 4] + (float)y[j + 4]) * 0.0625f;
            *(f32x4*)(amean + (size_t)i * 8) = o0;
            *(f32x4*)(amean + (size_t)i * 8 + 4) = o1;
        }
    }
}
#undef STAGE

// K-fragment loader: dst[kfr][dk], 4 x 16B global loads
#define LK(dst, kt) do {                                                          \
        const _Float16* kp_ = Kb + (size_t)((kt) * 32) * 1024;                    \
        _Pragma("unroll")                                                         \
        for (int kfr_ = 0; kfr_ < 2; kfr_++)                                      \
            _Pragma("unroll")                                                     \
            for (int dk_ = 0; dk_ < 2; dk_++)                                     \
                dst[kfr_][dk_] = *(const half8*)(kp_ + (size_t)(kfr_ * 16 + lr) * 1024 \
                                                 + ch + dk_ * 32 + lh * 8);       \
    } while (0)

#define SBODY(KF) do {                                                            \
        f32x4 sc[2][2] = {};                                                      \
        _Pragma("unroll")                                                         \
        for (int m = 0; m < 2; m++)                                               \
            _Pragma("unroll")                                                     \
            for (int kfr = 0; kfr < 2; kfr++)                                     \
                _Pragma("unroll")                                                 \
                for (int dk = 0; dk < 2; dk++)                                    \
                    sc[m][kfr] = __builtin_amdgcn_mfma_f32_16x16x32_f16(          \
                        qf[m][dk], KF[kfr][dk], sc[m][kfr], 0, 0, 0);             \
        _Pragma("unroll")                                                         \
        for (int m = 0; m < 2; m++)                                               \
            _Pragma("unroll")                                                     \
            for (int j = 0; j < 4; j++)                                           \
                sl[m][j] += __builtin_amdgcn_exp2f(sc[m][0][j])                   \
                          + __builtin_amdgcn_exp2f(sc[m][1][j]);                  \
    } while (0)

// ---- fused attention: phase 1 denominators, phase 2 emit (swapped QK^T,
// packed LDS, parity dbuf, LDS-only barrier). Grid 512 = 2 blocks/CU.
__global__ __launch_bounds__(512, 4)
void attn_fused(const _Float16* __restrict__ Qh, const _Float16* __restrict__ Kh,
                const _Float16* __restrict__ VT, _Float16* __restrict__ attnp,
                _Float16* __restrict__ Op)
{
    const int blk = blockIdx.x;
    const int b = blk & 3;
    const int hg = (blk >> 2) & 1;
    const int q0 = (blk >> 3) << 5;
    const int tid = threadIdx.x;
    const int l = tid & 63, w = tid >> 6;
    const int lr = l & 15, lh = l >> 4;
    const int ch = (hg * 8 + w) * 64;

    __shared__ __align__(16) _Float16 Pld[2][8][32][40];

    const size_t base = (size_t)b * 2048 * 1024;
    const _Float16* Qb = Qh + base;
    const _Float16* Kb = Kh + base;

    half8 qf[2][2];
#pragma unroll
    for (int m = 0; m < 2; m++)
#pragma unroll
        for (int dk = 0; dk < 2; dk++)
            qf[m][dk] = *(const half8*)(Qb + (size_t)(q0 + m * 16 + lr) * 1024
                                        + ch + dk * 32 + lh * 8);

    // ---- phase 1 ----
    float sl[2][4] = {};
    {
        half8 ka[2][2], kb2[2][2];
        LK(ka, 0);
        for (int kt = 0; kt < 64; kt += 2) {
            LK(kb2, kt + 1);
            SBODY(ka);
            LK(ka, kt + 2 < 64 ? kt + 2 : 63);
            SBODY(kb2);
        }
    }
#pragma unroll
    for (int m = 0; m < 2; m++)
#pragma unroll
        for (int j = 0; j < 4; j++) {
            float s = sl[m][j];
#pragma unroll
            for (int d = 1; d < 16; d <<= 1)
                s += __shfl_xor(s, d, 64);
            sl[m][j] = s;
        }
    float rinv[2];
#pragma unroll
    for (int m = 0; m < 2; m++) {
        int src = (lr >> 2) << 4;
        float t0 = __shfl(sl[m][0], src, 64);
        float t1 = __shfl(sl[m][1], src, 64);
        float t2 = __shfl(sl[m][2], src, 64);
        float t3 = __shfl(sl[m][3], src, 64);
        int jj = lr & 3;
        float s = (jj == 0) ? t0 : (jj == 1) ? t1 : (jj == 2) ? t2 : t3;
        rinv[m] = 1.0f / s;
    }

    // ---- phase 2 ----
    f32x4 oacc[2][4] = {};
    half8 ka[2][2], kb2[2][2];

#define EBODY(KF, KT, P) do {                                                     \
        const int krow = (KT) * 32;                                               \
        f32x4 sc[2][2] = {};                                                      \
        _Pragma("unroll")                                                         \
        for (int m = 0; m < 2; m++)                                               \
            _Pragma("unroll")                                                     \
            for (int kfr = 0; kfr < 2; kfr++)                                     \
                _Pragma("unroll")                                                 \
                for (int dk = 0; dk < 2; dk++)                                    \
                    sc[m][kfr] = __builtin_amdgcn_mfma_f32_16x16x32_f16(          \
                        KF[kfr][dk], qf[m][dk], sc[m][kfr], 0, 0, 0);             \
        _Pragma("unroll")                                                         \
        for (int m = 0; m < 2; m++)                                               \
            _Pragma("unroll")                                                     \
            for (int kfr = 0; kfr < 2; kfr++) {                                   \
                half4 pk4;                                                        \
                _Pragma("unroll")                                                 \
                for (int j = 0; j < 4; j++)                                       \
                    pk4[j] = (_Float16)(__builtin_amdgcn_exp2f(sc[m][kfr][j])     \
                                        * rinv[m]);                               \
                *(half4*)&Pld[P][w][m * 16 + lr][kfr * 16 + lh * 4] = pk4;        \
            }                                                                     \
        half8 vf[4], pa[2];                                                       \
        _Pragma("unroll")                                                         \
        for (int dv = 0; dv < 4; dv++)                                            \
            vf[dv] = *(const half8*)(VT + (((size_t)(b * 64 + dv * 16 + lr)) << 11) + krow + lh * 8); \
        _Pragma("unroll")                                                         \
        for (int m = 0; m < 2; m++)                                               \
            pa[m] = *(const half8*)&Pld[P][w][m * 16 + lr][lh * 8];               \
        _Pragma("unroll")                                                         \
        for (int m = 0; m < 2; m++)                                               \
            _Pragma("unroll")                                                     \
            for (int dv = 0; dv < 4; dv++)                                        \
                oacc[m][dv] = __builtin_amdgcn_mfma_f32_16x16x32_f16(             \
                    pa[m], vf[dv], oacc[m][dv], 0, 0, 0);                         \
        LDS_BARRIER();                                                            \
        {                                                                         \
            int r = tid >> 4, c2 = (tid & 15) * 2;                                \
            float s0 = 0.f, s1 = 0.f;                                             \
            _Pragma("unroll")                                                     \
            for (int ww = 0; ww < 8; ww++) {                                      \
                union { uint32_t u; _Float16 h[2]; } pv;                          \
                pv.u = *(const uint32_t*)&Pld[P][ww][r][c2];                      \
                s0 += (float)pv.h[0]; s1 += (float)pv.h[1];                       \
            }                                                                     \
            union { _Float16 h[2]; uint32_t u; } pk;                              \
            pk.h[0] = (_Float16)s0; pk.h[1] = (_Float16)s1;                       \
            __builtin_nontemporal_store(pk.u, (uint32_t*)(attnp                   \
                + (size_t)hg * 16777216 + (((size_t)(b * 2048 + q0 + r)) << 11)   \
                + krow + c2));                                                    \
        }                                                                         \
    } while (0)

    LK(ka, 0);
    for (int i = 0; i < 64; i += 2) {
        LK(kb2, i + 1);
        EBODY(ka, i, 0);
        LK(ka, i + 2 < 64 ? i + 2 : 63);
        EBODY(kb2, i + 1, 1);
    }
#undef EBODY

    _Float16* op = Op + base;
#pragma unroll
    for (int m = 0; m < 2; m++)
#pragma unroll
        for (int dv = 0; dv < 4; dv++)
#pragma unroll
            for (int j = 0; j < 4; j++) {
                int row = q0 + m * 16 + lh * 4 + j;
                int col = ch + dv * 16 + lr;
                op[(size_t)row * 1024 + col] = (_Float16)oacc[m][dv][j];
            }
}

extern "C" void kernel_launch(void* const* d_in, const int* in_sizes, int n_in,
                              void* d_out, int out_size, void* d_ws, size_t ws_size,
                              hipStream_t stream)
{
    const float* q  = (const float*)d_in[0];
    const float* k  = (const float*)d_in[1];
    const float* v  = (const float*)d_in[2];
    const float* Wq = (const float*)d_in[3];
    const float* bq = (const float*)d_in[4];
    const float* Wk = (const float*)d_in[5];
    const float* bk = (const float*)d_in[6];
    const float* Wv = (const float*)d_in[7];
    const float* bv = (const float*)d_in[8];
    const float* Wo = (const float*)d_in[9];
    const float* bo = (const float*)d_in[10];

    float* y = (float*)d_out;
    float* attn_mean = y + (size_t)4 * 2048 * 1024;

    uint8_t* ws = (uint8_t*)d_ws;
    _Float16* Qh  = (_Float16*)(ws);                         // 16 MB @ 0
    _Float16* Kh  = (_Float16*)(ws + 16777216);              // 16 MB
    _Float16* VT  = (_Float16*)(ws + 33554432);              // 1 MB
    _Float16* Wqc = (_Float16*)(ws + 34603008);              // 2 MB
    _Float16* Wkc = (_Float16*)(ws + 36700160);              // 2 MB
    _Float16* Woc = (_Float16*)(ws + 38797312);              // 2 MB
    _Float16* qc  = (_Float16*)(ws + 40894464);              // 16 MB (becomes Op)
    _Float16* kc  = (_Float16*)(ws + 57671680);              // 16 MB
    _Float16* Op  = qc;
    _Float16* attnp = (_Float16*)(ws + 74448896);            // 64 MB (2 hg partials)

    const float QS = 0.125f * 1.44269504088896340736f;

    prep_kernel<<<dim3(2176), dim3(256), 0, stream>>>(
        v, Wv, bv, VT, q, qc, k, kc, Wq, Wqc, Wk, Wkc, Wo, Woc);

    gemm16_dual<<<dim3(64, 8, 2), dim3(256), 0, stream>>>(
        qc, Wqc, bq, QS, Qh, kc, Wkc, bk, 1.0f, Kh, 8192, 1024, 1024);

    attn_fused<<<dim3(512), dim3(512), 0, stream>>>(Qh, Kh, VT, attnp, Op);

    ygc_kernel<<<dim3(1024), dim3(256), 0, stream>>>(
        Op, Woc, bo, 1.0f, y, 8192, 1024, 1024,
        attnp, attnp + (size_t)16777216, attn_mean, 2097152);
}